// Round 5
// baseline (91.478 us; speedup 1.0000x reference)
//
#include <hip/hip_runtime.h>
#include <math.h>

#define BLK 256

// tanh(x) = 1 - 2/(e^{2x}+1); clamp so __expf never overflows.
__device__ __forceinline__ float fast_tanh(float x) {
    x = fminf(9.0f, fmaxf(-9.0f, x));
    float e = __expf(2.0f * x);
    return fmaf(-2.0f, __builtin_amdgcn_rcpf(e + 1.0f), 1.0f);
}

// hw v_sin/v_cos operate on revolutions; v_fract does the range reduction.
__device__ __forceinline__ void fast_sincos(float x, float& s, float& c) {
    const float INV2PI = 0.15915494309189535f;
    float r = __builtin_amdgcn_fractf(x * INV2PI);
    s = __builtin_amdgcn_sinf(r);
    c = __builtin_amdgcn_cosf(r);
}

__global__ __launch_bounds__(BLK) void fk_fused_kernel(
    const float* __restrict__ joints,    // [B,7]
    const float* __restrict__ fk_params, // [7,4] : alpha, a, d, offset
    const float* __restrict__ W1, const float* __restrict__ b1,  // [15,7],[15]
    const float* __restrict__ W2, const float* __restrict__ b2,  // [15,15],[15]
    const float* __restrict__ W3, const float* __restrict__ b3,  // [7,15],[7]
    float* __restrict__ out,             // [B,3]
    int B)
{
    __shared__ float sJ[BLK * 7];   // joints staging, reused for output staging

    const int t = threadIdx.x;
    const int base = blockIdx.x * BLK;
    const bool full = (B - base) >= BLK;   // uniform per block

    // ---- stage this block's joints, coalesced ----
    if (full) {
        const float4* gsrc = (const float4*)(joints + base * 7);
        float4* ldst = (float4*)sJ;
        ldst[t] = gsrc[t];
        { int i = t + BLK; if (i < (BLK * 7) / 4) ldst[i] = gsrc[i]; }
    } else {
        const int nval = (B - base) * 7;
        for (int i = t; i < nval; i += BLK) sJ[i] = joints[base * 7 + i];
    }
    __syncthreads();

    const int sample = base + t;
    const bool active = full || (sample < B);
    float r0[4], r1[4], r2[4];   // rows 0..2 of ee (row 3 stays [0,0,0,1])

    if (active) {
        float j[7];
        #pragma unroll
        for (int k = 0; k < 7; ++k) j[k] = sJ[t * 7 + k];

        // ---- layer 1: 7 -> 15. Weights wave-uniform -> scalar loads. ----
        float h1[15];
        #pragma unroll
        for (int i = 0; i < 15; ++i) {
            float s = b1[i];
            #pragma unroll
            for (int k = 0; k < 7; ++k) s = fmaf(j[k], W1[i * 7 + k], s);
            h1[i] = fast_tanh(s);
        }
        // ---- layer 2: 15 -> 15 ----
        float h2[15];
        #pragma unroll
        for (int i = 0; i < 15; ++i) {
            float s = b2[i];
            #pragma unroll
            for (int k = 0; k < 15; ++k) s = fmaf(h1[k], W2[i * 15 + k], s);
            h2[i] = fast_tanh(s);
        }

        // ---- layer 3 (7 outputs) fused with DH chain ----
        #pragma unroll
        for (int jj = 0; jj < 7; ++jj) {
            float s = b3[jj];
            #pragma unroll
            for (int k = 0; k < 15; ++k) s = fmaf(h2[k], W3[jj * 15 + k], s);
            float corr = fast_tanh(s);

            const float alpha = fk_params[jj * 4 + 0];
            const float a     = fk_params[jj * 4 + 1];
            const float d     = fk_params[jj * 4 + 2];
            const float off   = fk_params[jj * 4 + 3];

            float th = j[jj] + corr + off;
            float st, ct, sa, ca;
            fast_sincos(th, st, ct);
            fast_sincos(alpha, sa, ca);

            const float m10 = st * ca, m11 = ct * ca, m13 = -d * sa;
            const float m20 = st * sa, m21 = ct * sa, m23 = ca * d;
            if (jj == 0) {
                r0[0] = ct;  r0[1] = -st; r0[2] = 0.0f; r0[3] = a;
                r1[0] = m10; r1[1] = m11; r1[2] = -sa;  r1[3] = m13;
                r2[0] = m20; r2[1] = m21; r2[2] = ca;   r2[3] = m23;
            } else {
                float n0, n1, n2, n3;
                n0 = r0[0]*ct + r0[1]*m10 + r0[2]*m20;
                n1 = -r0[0]*st + r0[1]*m11 + r0[2]*m21;
                n2 =             r0[1]*-sa + r0[2]*ca;
                n3 = r0[0]*a  + r0[1]*m13 + r0[2]*m23 + r0[3];
                r0[0]=n0; r0[1]=n1; r0[2]=n2; r0[3]=n3;
                n0 = r1[0]*ct + r1[1]*m10 + r1[2]*m20;
                n1 = -r1[0]*st + r1[1]*m11 + r1[2]*m21;
                n2 =             r1[1]*-sa + r1[2]*ca;
                n3 = r1[0]*a  + r1[1]*m13 + r1[2]*m23 + r1[3];
                r1[0]=n0; r1[1]=n1; r1[2]=n2; r1[3]=n3;
                n0 = r2[0]*ct + r2[1]*m10 + r2[2]*m20;
                n1 = -r2[0]*st + r2[1]*m11 + r2[2]*m21;
                n2 =             r2[1]*-sa + r2[2]*ca;
                n3 = r2[0]*a  + r2[1]*m13 + r2[2]*m23 + r2[3];
                r2[0]=n0; r2[1]=n1; r2[2]=n2; r2[3]=n3;
            }
        }
    }

    // ---- stage outputs through LDS, write coalesced ----
    __syncthreads();           // done reading sJ as joints
    if (active) {
        sJ[t * 3 + 0] = r0[3];
        sJ[t * 3 + 1] = r1[3];
        sJ[t * 3 + 2] = r2[3];
    }
    __syncthreads();
    if (full) {
        float4* gdst = (float4*)(out + base * 3);
        const float4* lsrc = (const float4*)sJ;
        if (t < (BLK * 3) / 4) gdst[t] = lsrc[t];
    } else {
        const int onval = (B - base) * 3;
        for (int i = t; i < onval; i += BLK) out[base * 3 + i] = sJ[i];
    }
}

extern "C" void kernel_launch(void* const* d_in, const int* in_sizes, int n_in,
                              void* d_out, int out_size, void* d_ws, size_t ws_size,
                              hipStream_t stream) {
    const float* joints    = (const float*)d_in[0];
    const float* fk_params = (const float*)d_in[1];
    const float* W1 = (const float*)d_in[2];
    const float* b1 = (const float*)d_in[3];
    const float* W2 = (const float*)d_in[4];
    const float* b2 = (const float*)d_in[5];
    const float* W3 = (const float*)d_in[6];
    const float* b3 = (const float*)d_in[7];
    float* out = (float*)d_out;

    const int B = in_sizes[0] / 7;
    const int nblk = (B + BLK - 1) / BLK;
    // MEASUREMENT ROUND: launch the identical kernel twice. The second launch
    // rewrites the same outputs (idempotent), so correctness is unchanged and
    // the marginal dur_us vs R4 equals the kernel's true duration — separating
    // kernel time from the harness's ws-poison/restore floor.
    fk_fused_kernel<<<nblk, BLK, 0, stream>>>(joints, fk_params, W1, b1, W2, b2,
                                              W3, b3, out, B);
    fk_fused_kernel<<<nblk, BLK, 0, stream>>>(joints, fk_params, W1, b1, W2, b2,
                                              W3, b3, out, B);
}

// Round 6
// 79.284 us; speedup vs baseline: 1.1538x; 1.1538x over previous
//
#include <hip/hip_runtime.h>
#include <math.h>

#define BLK 256

// tanh(x) = 1 - 2/(e^{2x}+1), NO clamp needed:
//   x large  -> e=+inf -> rcp(inf)=0 -> 1   (exact limit)
//   x small  -> e->0   -> rcp(1)=1  -> -1   (exact limit)
__device__ __forceinline__ float fast_tanh(float x) {
    float e = __expf(2.0f * x);
    return fmaf(-2.0f, __builtin_amdgcn_rcpf(e + 1.0f), 1.0f);
}

// hw v_sin/v_cos operate on revolutions; v_fract does the range reduction.
__device__ __forceinline__ void fast_sincos(float x, float& s, float& c) {
    const float INV2PI = 0.15915494309189535f;
    float r = __builtin_amdgcn_fractf(x * INV2PI);
    s = __builtin_amdgcn_sinf(r);
    c = __builtin_amdgcn_cosf(r);
}

__global__ __launch_bounds__(BLK) void fk_fused_kernel(
    const float* __restrict__ joints,    // [B,7]
    const float* __restrict__ fk_params, // [7,4] : alpha, a, d, offset
    const float* __restrict__ W1, const float* __restrict__ b1,  // [15,7],[15]
    const float* __restrict__ W2, const float* __restrict__ b2,  // [15,15],[15]
    const float* __restrict__ W3, const float* __restrict__ b3,  // [7,15],[7]
    float* __restrict__ out,             // [B,3]
    int B)
{
    __shared__ float sJ[BLK * 7];   // joints staging, reused for output staging

    const int t = threadIdx.x;
    const int base = blockIdx.x * BLK;
    const bool full = (B - base) >= BLK;   // uniform per block

    // ---- stage this block's joints, coalesced ----
    if (full) {
        const float4* gsrc = (const float4*)(joints + base * 7);
        float4* ldst = (float4*)sJ;
        ldst[t] = gsrc[t];
        { int i = t + BLK; if (i < (BLK * 7) / 4) ldst[i] = gsrc[i]; }
    } else {
        const int nval = (B - base) * 7;
        for (int i = t; i < nval; i += BLK) sJ[i] = joints[base * 7 + i];
    }
    __syncthreads();

    const int sample = base + t;
    const bool active = full || (sample < B);
    float v0 = 0.f, v1 = 0.f, v2 = 0.f;   // position column accumulator

    if (active) {
        float j[7];
        #pragma unroll
        for (int k = 0; k < 7; ++k) j[k] = sJ[t * 7 + k];

        // ---- layer 1: 7 -> 15. Weights wave-uniform -> scalar loads. ----
        float h1[15];
        #pragma unroll
        for (int i = 0; i < 15; ++i) {
            float s = b1[i];
            #pragma unroll
            for (int k = 0; k < 7; ++k) s = fmaf(j[k], W1[i * 7 + k], s);
            h1[i] = fast_tanh(s);
        }
        // ---- layer 2: 15 -> 15 ----
        float h2[15];
        #pragma unroll
        for (int i = 0; i < 15; ++i) {
            float s = b2[i];
            #pragma unroll
            for (int k = 0; k < 15; ++k) s = fmaf(h1[k], W2[i * 15 + k], s);
            h2[i] = fast_tanh(s);
        }

        // ---- layer 3: all 7 corrected angles th[jj] ----
        float th[7];
        #pragma unroll
        for (int jj = 0; jj < 7; ++jj) {
            float s = b3[jj];
            #pragma unroll
            for (int k = 0; k < 15; ++k) s = fmaf(h2[k], W3[jj * 15 + k], s);
            th[jj] = j[jj] + fast_tanh(s) + fk_params[jj * 4 + 3];
        }

        // ---- DH chain, position column only, right-to-left:
        //      P = M0·M1·...·M6, want P[0:3,3].
        //      v = M6[:,3]; then v = M_jj · v for jj = 5..0.
        //      row0=[ct,-st,0,a] row1=[st*ca,ct*ca,-sa,-d*sa] row2=[st*sa,ct*sa,ca,ca*d]
        #pragma unroll
        for (int jj = 6; jj >= 0; --jj) {
            const float alpha = fk_params[jj * 4 + 0];
            const float a     = fk_params[jj * 4 + 1];
            const float d     = fk_params[jj * 4 + 2];
            float st, ct, sa, ca;
            fast_sincos(th[jj], st, ct);
            fast_sincos(alpha, sa, ca);
            if (jj == 6) {
                v0 = a;
                v1 = -d * sa;
                v2 = d * ca;
            } else {
                const float t1 = fmaf(st, v0, ct * v1);   // st*v0 + ct*v1
                const float u  = v2 + d;
                const float n0 = fmaf(ct, v0, fmaf(-st, v1, a));
                v1 = fmaf(ca, t1, -sa * u);
                v2 = fmaf(sa, t1, ca * u);
                v0 = n0;
            }
        }
    }

    // ---- stage outputs through LDS, write coalesced ----
    __syncthreads();           // done reading sJ as joints
    if (active) {
        sJ[t * 3 + 0] = v0;
        sJ[t * 3 + 1] = v1;
        sJ[t * 3 + 2] = v2;
    }
    __syncthreads();
    if (full) {
        float4* gdst = (float4*)(out + base * 3);
        const float4* lsrc = (const float4*)sJ;
        if (t < (BLK * 3) / 4) gdst[t] = lsrc[t];
    } else {
        const int onval = (B - base) * 3;
        for (int i = t; i < onval; i += BLK) out[base * 3 + i] = sJ[i];
    }
}

extern "C" void kernel_launch(void* const* d_in, const int* in_sizes, int n_in,
                              void* d_out, int out_size, void* d_ws, size_t ws_size,
                              hipStream_t stream) {
    const float* joints    = (const float*)d_in[0];
    const float* fk_params = (const float*)d_in[1];
    const float* W1 = (const float*)d_in[2];
    const float* b1 = (const float*)d_in[3];
    const float* W2 = (const float*)d_in[4];
    const float* b2 = (const float*)d_in[5];
    const float* W3 = (const float*)d_in[6];
    const float* b3 = (const float*)d_in[7];
    float* out = (float*)d_out;

    const int B = in_sizes[0] / 7;
    const int nblk = (B + BLK - 1) / BLK;
    fk_fused_kernel<<<nblk, BLK, 0, stream>>>(joints, fk_params, W1, b1, W2, b2,
                                              W3, b3, out, B);
}